// Round 1
// baseline (662.845 us; speedup 1.0000x reference)
//
#include <hip/hip_runtime.h>
#include <cstdint>

// Problem constants: B=16, C=256, H=32 -> N=1024 tokens, HEADS=8, HS=32, D=256
#define PERB 262144   // C*H*H = N*D elements per batch

__device__ __forceinline__ void fma4(float4& a, float s, const float4& b) {
    a.x += s * b.x; a.y += s * b.y; a.z += s * b.z; a.w += s * b.w;
}

// ---------------------------------------------------------------------------
// Kernel 1: LayerNorm over channel axis. x [B,256,1024] -> X same flat layout
// (which IS the [B, 1024, 256] raw view used by the projections).
// Block: 256 thr = 64 spatial positions x 4 channel-groups. Grid: 256.
// ---------------------------------------------------------------------------
__global__ __launch_bounds__(256) void ln_kernel(
    const float* __restrict__ x, const float* __restrict__ gam,
    const float* __restrict__ bet, float* __restrict__ X)
{
    const int blk = blockIdx.x;        // b*16 + spblock
    const int b   = blk >> 4;
    const int sp0 = (blk & 15) << 6;
    const int tid = threadIdx.x;
    const int spl = tid & 63;          // spatial within block
    const int cg  = tid >> 6;          // channel group 0..3
    const int c0  = cg << 6;
    const int sp  = sp0 + spl;
    const float* xb = x + (size_t)b * PERB + sp;

    float vals[64];
    float s = 0.f, sq = 0.f;
#pragma unroll
    for (int i = 0; i < 64; ++i) {
        float v = xb[(size_t)(c0 + i) * 1024];   // coalesced across lanes
        vals[i] = v; s += v; sq += v * v;
    }
    __shared__ float rs[4][64];
    __shared__ float rq[4][64];
    rs[cg][spl] = s; rq[cg][spl] = sq;
    __syncthreads();
    const float ts = rs[0][spl] + rs[1][spl] + rs[2][spl] + rs[3][spl];
    const float tq = rq[0][spl] + rq[1][spl] + rq[2][spl] + rq[3][spl];
    const float mean = ts * (1.f / 256.f);
    const float var  = tq * (1.f / 256.f) - mean * mean;
    const float rstd = rsqrtf(var + 1e-5f);

    float* Xb = X + (size_t)b * PERB + sp;
#pragma unroll
    for (int i = 0; i < 64; ++i) {
        const int c = c0 + i;
        Xb[(size_t)c * 1024] = (vals[i] - mean) * rstd * gam[c] + bet[c];
    }
}

// ---------------------------------------------------------------------------
// Kernel 2: fused Q/K/V projection. out[m,n] = sum_k X[m,k]*W[n,k] + b[n].
// M=16384, N=256, K=256. Tile 64x64, 4x4 per thread, 3 outputs share A tile.
// Grid: 256 mtiles * 4 ntiles = 1024 blocks, 256 threads.
// ---------------------------------------------------------------------------
__global__ __launch_bounds__(256) void qkv_kernel(
    const float* __restrict__ X,
    const float* __restrict__ wq, const float* __restrict__ bq,
    const float* __restrict__ wk, const float* __restrict__ bk,
    const float* __restrict__ wv, const float* __restrict__ bv,
    float* __restrict__ Q, float* __restrict__ K, float* __restrict__ V)
{
    __shared__ __align__(16) float As[16][68];
    __shared__ __align__(16) float Bq[16][68];
    __shared__ __align__(16) float Bk[16][68];
    __shared__ __align__(16) float Bv[16][68];
    const int blk = blockIdx.x;
    const int m0  = (blk >> 2) << 6;
    const int n0  = (blk & 3) << 6;
    const int tid = threadIdx.x;
    const int tm  = tid & 15, tn = tid >> 4;
    const int mi  = tid >> 2, ki = (tid & 3) << 2;

    float4 accq[4], acck[4], accv[4];
#pragma unroll
    for (int i = 0; i < 4; ++i) {
        accq[i] = make_float4(0.f, 0.f, 0.f, 0.f);
        acck[i] = make_float4(0.f, 0.f, 0.f, 0.f);
        accv[i] = make_float4(0.f, 0.f, 0.f, 0.f);
    }

    for (int kc = 0; kc < 16; ++kc) {
        const int k0 = kc << 4;
        const float4 a  = *(const float4*)&X [(size_t)(m0 + mi) * 256 + k0 + ki];
        const float4 q4 = *(const float4*)&wq[(size_t)(n0 + mi) * 256 + k0 + ki];
        const float4 k4 = *(const float4*)&wk[(size_t)(n0 + mi) * 256 + k0 + ki];
        const float4 v4 = *(const float4*)&wv[(size_t)(n0 + mi) * 256 + k0 + ki];
        __syncthreads();
        As[ki + 0][mi] = a.x;  As[ki + 1][mi] = a.y;
        As[ki + 2][mi] = a.z;  As[ki + 3][mi] = a.w;
        Bq[ki + 0][mi] = q4.x; Bq[ki + 1][mi] = q4.y;
        Bq[ki + 2][mi] = q4.z; Bq[ki + 3][mi] = q4.w;
        Bk[ki + 0][mi] = k4.x; Bk[ki + 1][mi] = k4.y;
        Bk[ki + 2][mi] = k4.z; Bk[ki + 3][mi] = k4.w;
        Bv[ki + 0][mi] = v4.x; Bv[ki + 1][mi] = v4.y;
        Bv[ki + 2][mi] = v4.z; Bv[ki + 3][mi] = v4.w;
        __syncthreads();
#pragma unroll
        for (int kk = 0; kk < 16; ++kk) {
            const float4 av = *(const float4*)&As[kk][tm << 2];
            const float4 b1 = *(const float4*)&Bq[kk][tn << 2];
            const float4 b2 = *(const float4*)&Bk[kk][tn << 2];
            const float4 b3 = *(const float4*)&Bv[kk][tn << 2];
            fma4(accq[0], av.x, b1); fma4(acck[0], av.x, b2); fma4(accv[0], av.x, b3);
            fma4(accq[1], av.y, b1); fma4(acck[1], av.y, b2); fma4(accv[1], av.y, b3);
            fma4(accq[2], av.z, b1); fma4(acck[2], av.z, b2); fma4(accv[2], av.z, b3);
            fma4(accq[3], av.w, b1); fma4(acck[3], av.w, b2); fma4(accv[3], av.w, b3);
        }
    }

    const int col = n0 + (tn << 2);
    const float4 bq4 = *(const float4*)&bq[col];
    const float4 bk4 = *(const float4*)&bk[col];
    const float4 bv4 = *(const float4*)&bv[col];
#pragma unroll
    for (int i = 0; i < 4; ++i) {
        const size_t row = (size_t)(m0 + (tm << 2) + i);
        float4 t;
        t = accq[i]; t.x += bq4.x; t.y += bq4.y; t.z += bq4.z; t.w += bq4.w;
        *(float4*)&Q[row * 256 + col] = t;
        t = acck[i]; t.x += bk4.x; t.y += bk4.y; t.z += bk4.z; t.w += bk4.w;
        *(float4*)&K[row * 256 + col] = t;
        t = accv[i]; t.x += bv4.x; t.y += bv4.y; t.z += bv4.z; t.w += bv4.w;
        *(float4*)&V[row * 256 + col] = t;
    }
}

// ---------------------------------------------------------------------------
// Kernel 3: attention. Per (b,h): Khat[s][n] = buf[base + s*1024 + n], s<32.
// One thread per query m; softmax over keys n (axis=-2 of dots); no max-sub
// (scores ~N(0,1), exp safe). Bias recomputed from (dy,dx) -- rel_idx unused.
// K/V staged in 64KB LDS (fp32, 4 phases of 256 keys), XOR-swizzled n-major
// so a column read is 8x ds_read_b128 broadcast, conflict-free.
// Grid: 256 blocks (b*16 + h*2 + mhalf) x 512 threads.
// ---------------------------------------------------------------------------
__global__ __launch_bounds__(512) void attn_kernel(
    const float* __restrict__ Q, const float* __restrict__ K,
    const float* __restrict__ V, const float* __restrict__ relb,
    float* __restrict__ O)
{
    __shared__ __align__(16) float Kl[8192];
    __shared__ __align__(16) float Vl[8192];
    const int blk = blockIdx.x;
    const int b   = blk >> 4;
    const int h   = (blk >> 1) & 7;
    const int tid = threadIdx.x;
    const int m   = ((blk & 1) << 9) | tid;
    const size_t base = (size_t)b * PERB + (size_t)h * 32768;
    const float* Qb  = Q + base;
    const float* Kb  = K + base;
    const float* Vb  = V + base;
    const float* rbh = relb + h * 3969;

    float q[32], o[32];
#pragma unroll
    for (int s = 0; s < 32; ++s) { q[s] = Qb[s * 1024 + m]; o[s] = 0.f; }
    float sum = 0.f;
    const int my = m >> 5, mx = m & 31;
    const float4* K4 = (const float4*)Kl;
    const float4* V4 = (const float4*)Vl;

    for (int ph = 0; ph < 4; ++ph) {
        const int nbase = ph << 8;
        __syncthreads();  // protect previous phase's reads
        for (int idx = tid; idx < 8192; idx += 512) {
            const int s = idx >> 8, nn = idx & 255;
            const int sw = (nn << 5) | ((((s >> 2) ^ (nn & 7)) << 2) | (s & 3));
            Kl[sw] = Kb[s * 1024 + nbase + nn];
            Vl[sw] = Vb[s * 1024 + nbase + nn];
        }
        __syncthreads();
        for (int nn = 0; nn < 256; ++nn) {
            const int xr = nn & 7;
            const int fb = nn << 3;
            float4 kc[8];
#pragma unroll
            for (int g = 0; g < 8; ++g) kc[g] = K4[fb + (g ^ xr)];
            float dp[4] = {0.f, 0.f, 0.f, 0.f};
#pragma unroll
            for (int g = 0; g < 8; ++g)
                dp[g & 3] += q[4*g + 0] * kc[g].x + q[4*g + 1] * kc[g].y
                           + q[4*g + 2] * kc[g].z + q[4*g + 3] * kc[g].w;
            const int n  = nbase + nn;
            const int dy = (n >> 5) - my + 31;
            const int dx = (n & 31) - mx + 31;
            const float bias = rbh[dy * 63 + dx];
            const float sc = (dp[0] + dp[1] + dp[2] + dp[3]) * 0.0625f + bias;
            const float p  = __expf(sc);
            sum += p;
#pragma unroll
            for (int g = 0; g < 8; ++g) {
                const float4 vv = V4[fb + (g ^ xr)];
                o[4*g + 0] += p * vv.x; o[4*g + 1] += p * vv.y;
                o[4*g + 2] += p * vv.z; o[4*g + 3] += p * vv.w;
            }
        }
    }
    const float inv = 1.0f / sum;
    float* Ob = O + base;
#pragma unroll
    for (int s = 0; s < 32; ++s) Ob[s * 1024 + m] = o[s] * inv;
}

// ---------------------------------------------------------------------------
// Kernel 4: output projection + bias + residual.
// out[g] = x[g] + sum_k O[m,k]*wo[c,k] + bo[c], g = m*256 + c (raw views line up)
// ---------------------------------------------------------------------------
__global__ __launch_bounds__(256) void oproj_kernel(
    const float* __restrict__ A, const float* __restrict__ wo,
    const float* __restrict__ bo, const float* __restrict__ x,
    float* __restrict__ out)
{
    __shared__ __align__(16) float As[16][68];
    __shared__ __align__(16) float Bs[16][68];
    const int blk = blockIdx.x;
    const int m0  = (blk >> 2) << 6;
    const int n0  = (blk & 3) << 6;
    const int tid = threadIdx.x;
    const int tm  = tid & 15, tn = tid >> 4;
    const int mi  = tid >> 2, ki = (tid & 3) << 2;

    float4 acc[4];
#pragma unroll
    for (int i = 0; i < 4; ++i) acc[i] = make_float4(0.f, 0.f, 0.f, 0.f);

    for (int kc = 0; kc < 16; ++kc) {
        const int k0 = kc << 4;
        const float4 a  = *(const float4*)&A [(size_t)(m0 + mi) * 256 + k0 + ki];
        const float4 w4 = *(const float4*)&wo[(size_t)(n0 + mi) * 256 + k0 + ki];
        __syncthreads();
        As[ki + 0][mi] = a.x;  As[ki + 1][mi] = a.y;
        As[ki + 2][mi] = a.z;  As[ki + 3][mi] = a.w;
        Bs[ki + 0][mi] = w4.x; Bs[ki + 1][mi] = w4.y;
        Bs[ki + 2][mi] = w4.z; Bs[ki + 3][mi] = w4.w;
        __syncthreads();
#pragma unroll
        for (int kk = 0; kk < 16; ++kk) {
            const float4 av = *(const float4*)&As[kk][tm << 2];
            const float4 b1 = *(const float4*)&Bs[kk][tn << 2];
            fma4(acc[0], av.x, b1);
            fma4(acc[1], av.y, b1);
            fma4(acc[2], av.z, b1);
            fma4(acc[3], av.w, b1);
        }
    }

    const int col = n0 + (tn << 2);
    const float4 bo4 = *(const float4*)&bo[col];
#pragma unroll
    for (int i = 0; i < 4; ++i) {
        const size_t row = (size_t)(m0 + (tm << 2) + i);
        const size_t g = row * 256 + col;
        const float4 r = *(const float4*)&x[g];
        float4 t = acc[i];
        t.x += bo4.x + r.x; t.y += bo4.y + r.y;
        t.z += bo4.z + r.z; t.w += bo4.w + r.w;
        *(float4*)&out[g] = t;
    }
}

// ---------------------------------------------------------------------------
extern "C" void kernel_launch(void* const* d_in, const int* in_sizes, int n_in,
                              void* d_out, int out_size, void* d_ws, size_t ws_size,
                              hipStream_t stream)
{
    (void)in_sizes; (void)n_in; (void)out_size; (void)ws_size;
    const float* x   = (const float*)d_in[0];
    const float* lng = (const float*)d_in[1];
    const float* lnb = (const float*)d_in[2];
    const float* wq  = (const float*)d_in[3];
    const float* bq  = (const float*)d_in[4];
    const float* wk  = (const float*)d_in[5];
    const float* bk  = (const float*)d_in[6];
    const float* wv  = (const float*)d_in[7];
    const float* bv  = (const float*)d_in[8];
    const float* wo  = (const float*)d_in[9];
    const float* bo  = (const float*)d_in[10];
    const float* rb  = (const float*)d_in[11];
    // d_in[12] (rel_idx) unused: index recomputed analytically in-kernel.

    float* ws = (float*)d_ws;                 // needs 5*4194304 floats = 80 MiB
    float* X = ws;
    float* Q = ws + 1 * 4194304;
    float* K = ws + 2 * 4194304;
    float* V = ws + 3 * 4194304;
    float* O = ws + 4 * 4194304;
    float* out = (float*)d_out;

    hipLaunchKernelGGL(ln_kernel,    dim3(256),  dim3(256), 0, stream, x, lng, lnb, X);
    hipLaunchKernelGGL(qkv_kernel,   dim3(1024), dim3(256), 0, stream,
                       X, wq, bq, wk, bk, wv, bv, Q, K, V);
    hipLaunchKernelGGL(attn_kernel,  dim3(256),  dim3(512), 0, stream, Q, K, V, rb, O);
    hipLaunchKernelGGL(oproj_kernel, dim3(1024), dim3(256), 0, stream, O, wo, bo, x, out);
}

// Round 2
// 269.388 us; speedup vs baseline: 2.4606x; 2.4606x over previous
//
#include <hip/hip_runtime.h>
#include <cstdint>

#define PERB 262144   // C*H*H = N*D elements per batch

typedef __attribute__((ext_vector_type(8))) short bf16x8;
typedef __attribute__((ext_vector_type(4))) float f32x4;

__device__ __forceinline__ void fma4(float4& a, float s, const float4& b) {
    a.x += s * b.x; a.y += s * b.y; a.z += s * b.z; a.w += s * b.w;
}

__device__ __forceinline__ uint16_t f2bf(float f) {
    uint32_t u = __float_as_uint(f);
    u += 0x7fff + ((u >> 16) & 1);   // RNE
    return (uint16_t)(u >> 16);
}

// ---------------------------------------------------------------------------
// Kernel 1: LayerNorm over channel axis (unchanged from round 0).
// ---------------------------------------------------------------------------
__global__ __launch_bounds__(256) void ln_kernel(
    const float* __restrict__ x, const float* __restrict__ gam,
    const float* __restrict__ bet, float* __restrict__ X)
{
    const int blk = blockIdx.x;
    const int b   = blk >> 4;
    const int sp0 = (blk & 15) << 6;
    const int tid = threadIdx.x;
    const int spl = tid & 63;
    const int cg  = tid >> 6;
    const int c0  = cg << 6;
    const int sp  = sp0 + spl;
    const float* xb = x + (size_t)b * PERB + sp;

    float vals[64];
    float s = 0.f, sq = 0.f;
#pragma unroll
    for (int i = 0; i < 64; ++i) {
        float v = xb[(size_t)(c0 + i) * 1024];
        vals[i] = v; s += v; sq += v * v;
    }
    __shared__ float rs[4][64];
    __shared__ float rq[4][64];
    rs[cg][spl] = s; rq[cg][spl] = sq;
    __syncthreads();
    const float ts = rs[0][spl] + rs[1][spl] + rs[2][spl] + rs[3][spl];
    const float tq = rq[0][spl] + rq[1][spl] + rq[2][spl] + rq[3][spl];
    const float mean = ts * (1.f / 256.f);
    const float var  = tq * (1.f / 256.f) - mean * mean;
    const float rstd = rsqrtf(var + 1e-5f);

    float* Xb = X + (size_t)b * PERB + sp;
#pragma unroll
    for (int i = 0; i < 64; ++i) {
        const int c = c0 + i;
        Xb[(size_t)c * 1024] = (vals[i] - mean) * rstd * gam[c] + bet[c];
    }
}

// ---------------------------------------------------------------------------
// Kernel 2: fused Q/K/V projection (unchanged from round 0).
// ---------------------------------------------------------------------------
__global__ __launch_bounds__(256) void qkv_kernel(
    const float* __restrict__ X,
    const float* __restrict__ wq, const float* __restrict__ bq,
    const float* __restrict__ wk, const float* __restrict__ bk,
    const float* __restrict__ wv, const float* __restrict__ bv,
    float* __restrict__ Q, float* __restrict__ K, float* __restrict__ V)
{
    __shared__ __align__(16) float As[16][68];
    __shared__ __align__(16) float Bq[16][68];
    __shared__ __align__(16) float Bk[16][68];
    __shared__ __align__(16) float Bv[16][68];
    const int blk = blockIdx.x;
    const int m0  = (blk >> 2) << 6;
    const int n0  = (blk & 3) << 6;
    const int tid = threadIdx.x;
    const int tm  = tid & 15, tn = tid >> 4;
    const int mi  = tid >> 2, ki = (tid & 3) << 2;

    float4 accq[4], acck[4], accv[4];
#pragma unroll
    for (int i = 0; i < 4; ++i) {
        accq[i] = make_float4(0.f, 0.f, 0.f, 0.f);
        acck[i] = make_float4(0.f, 0.f, 0.f, 0.f);
        accv[i] = make_float4(0.f, 0.f, 0.f, 0.f);
    }

    for (int kc = 0; kc < 16; ++kc) {
        const int k0 = kc << 4;
        const float4 a  = *(const float4*)&X [(size_t)(m0 + mi) * 256 + k0 + ki];
        const float4 q4 = *(const float4*)&wq[(size_t)(n0 + mi) * 256 + k0 + ki];
        const float4 k4 = *(const float4*)&wk[(size_t)(n0 + mi) * 256 + k0 + ki];
        const float4 v4 = *(const float4*)&wv[(size_t)(n0 + mi) * 256 + k0 + ki];
        __syncthreads();
        As[ki + 0][mi] = a.x;  As[ki + 1][mi] = a.y;
        As[ki + 2][mi] = a.z;  As[ki + 3][mi] = a.w;
        Bq[ki + 0][mi] = q4.x; Bq[ki + 1][mi] = q4.y;
        Bq[ki + 2][mi] = q4.z; Bq[ki + 3][mi] = q4.w;
        Bk[ki + 0][mi] = k4.x; Bk[ki + 1][mi] = k4.y;
        Bk[ki + 2][mi] = k4.z; Bk[ki + 3][mi] = k4.w;
        Bv[ki + 0][mi] = v4.x; Bv[ki + 1][mi] = v4.y;
        Bv[ki + 2][mi] = v4.z; Bv[ki + 3][mi] = v4.w;
        __syncthreads();
#pragma unroll
        for (int kk = 0; kk < 16; ++kk) {
            const float4 av = *(const float4*)&As[kk][tm << 2];
            const float4 b1 = *(const float4*)&Bq[kk][tn << 2];
            const float4 b2 = *(const float4*)&Bk[kk][tn << 2];
            const float4 b3 = *(const float4*)&Bv[kk][tn << 2];
            fma4(accq[0], av.x, b1); fma4(acck[0], av.x, b2); fma4(accv[0], av.x, b3);
            fma4(accq[1], av.y, b1); fma4(acck[1], av.y, b2); fma4(accv[1], av.y, b3);
            fma4(accq[2], av.z, b1); fma4(acck[2], av.z, b2); fma4(accv[2], av.z, b3);
            fma4(accq[3], av.w, b1); fma4(acck[3], av.w, b2); fma4(accv[3], av.w, b3);
        }
    }

    const int col = n0 + (tn << 2);
    const float4 bq4 = *(const float4*)&bq[col];
    const float4 bk4 = *(const float4*)&bk[col];
    const float4 bv4 = *(const float4*)&bv[col];
#pragma unroll
    for (int i = 0; i < 4; ++i) {
        const size_t row = (size_t)(m0 + (tm << 2) + i);
        float4 t;
        t = accq[i]; t.x += bq4.x; t.y += bq4.y; t.z += bq4.z; t.w += bq4.w;
        *(float4*)&Q[row * 256 + col] = t;
        t = acck[i]; t.x += bk4.x; t.y += bk4.y; t.z += bk4.z; t.w += bk4.w;
        *(float4*)&K[row * 256 + col] = t;
        t = accv[i]; t.x += bv4.x; t.y += bv4.y; t.z += bv4.z; t.w += bv4.w;
        *(float4*)&V[row * 256 + col] = t;
    }
}

// ---------------------------------------------------------------------------
// Kernel 3: MFMA flash attention.
// Per (b,h): Khat[s][n] = buf[base + s*1024 + n], s<32 (same for Q,V).
// Block = (b,h,mtile): 128 queries. Loop 16 chunks of 64 keys:
//   S[n][m] = sum_s K[s][n] Q[s][m]  via mfma_16x16x32 (A=K^T frag, B=Q frag)
//   P = exp(S/16 + bias(dy,dx)), denominator accumulated per-lane
//   O[s][m] += sum_n V[s][n] P[n][m] via mfma (A=V frag, B=P frag, LDS round-trip)
// No max-subtraction: scores are bias-dominated, |score| <~ 6.
// Grid: blk = mtile*128 + (b*8+h) so the 8 m-tiles sharing (b,h) hit one XCD.
// ---------------------------------------------------------------------------
__global__ __launch_bounds__(256, 3) void attn_kernel(
    const float* __restrict__ Q, const float* __restrict__ K,
    const float* __restrict__ V, const float* __restrict__ relb,
    float* __restrict__ O)
{
    // LDS layout (bytes):
    //   [0, 18432)      Plds: P bf16, addr = m*144 + n*2   (m<128, n<64)
    //                   (start of block: reused as Qlds, addr = q*2048 + mm*16)
    //   [18432, 22528)  Klds: bf16 granules, addr = q*1024 + nn*16  (q = s>>3)
    //   [22528, 27136)  Vlds: bf16, addr = s*144 + nn*2
    //   [27136, 29184)  red:  4 waves x 8 msub x 16 cols, fp32
    __shared__ __align__(16) unsigned char smem[29184];
    char* Pbase = (char*)smem;
    char* Kbase = (char*)smem + 18432;
    char* Vbase = (char*)smem + 22528;
    float* red  = (float*)(smem + 27136);

    const int blk = blockIdx.x;
    const int bh  = blk & 127;
    const int mt  = blk >> 7;          // 0..7
    const int b   = bh >> 3;
    const int h   = bh & 7;
    const int m0  = mt << 7;           // query tile base
    const int tid = threadIdx.x;
    const int w    = tid >> 6;         // wave 0..3
    const int lane = tid & 63;
    const int quad = lane >> 4;
    const int c    = lane & 15;

    const size_t base = (size_t)b * PERB + (size_t)h * 32768;
    const float* Qb  = Q + base;
    const float* Kb  = K + base;
    const float* Vb  = V + base;
    const float* rbh = relb + h * 3969;

    // ---- stage Q [32s x 128m] -> Qlds (in Pbase region), granule layout ----
    {
        const int mm = tid & 127;
        const int sg = tid >> 7;          // 0..1 -> s = sg*16 + j
        union { bf16x8 v; uint16_t u[8]; } g0, g1;
#pragma unroll
        for (int j = 0; j < 8; ++j)
            g0.u[j] = f2bf(Qb[(size_t)(sg * 16 + j) * 1024 + m0 + mm]);
#pragma unroll
        for (int j = 0; j < 8; ++j)
            g1.u[j] = f2bf(Qb[(size_t)(sg * 16 + 8 + j) * 1024 + m0 + mm]);
        *(bf16x8*)(Pbase + (sg * 2 + 0) * 2048 + mm * 16) = g0.v;
        *(bf16x8*)(Pbase + (sg * 2 + 1) * 2048 + mm * 16) = g1.v;
    }
    __syncthreads();
    // Q B-fragments: lane holds Q[s = quad*8 + j][m = msub*16 + c]
    bf16x8 qfrag[8];
#pragma unroll
    for (int msub = 0; msub < 8; ++msub)
        qfrag[msub] = *(const bf16x8*)(Pbase + quad * 2048 + (msub * 16 + c) * 16);

    // per-msub query coords for bias
    int my[8], mx[8];
#pragma unroll
    for (int msub = 0; msub < 8; ++msub) {
        const int m = m0 + msub * 16 + c;
        my[msub] = m >> 5; mx[msub] = m & 31;
    }

    f32x4 oacc[2][2];
#pragma unroll
    for (int i = 0; i < 2; ++i)
#pragma unroll
        for (int j = 0; j < 2; ++j)
            oacc[i][j] = (f32x4){0.f, 0.f, 0.f, 0.f};
    float dsum[8];
#pragma unroll
    for (int i = 0; i < 8; ++i) dsum[i] = 0.f;

    // staging thread coords
    const int knn = tid & 63, ksg = (tid >> 6) & 3;    // K: 8 s-vals for col knn
    const int vs = tid >> 3, vng = tid & 7;            // V: 8 n-vals for row vs

    for (int ch = 0; ch < 16; ++ch) {
        const int n0c = ch << 6;
        __syncthreads();   // prev chunk's Plds/Vlds reads done (also Q frag reads, ch0)

        // ---- stage K chunk: Klds granule(q=s>>3, nn), contiguous writes ----
        {
            union { bf16x8 v; uint16_t u[8]; } g;
#pragma unroll
            for (int j = 0; j < 8; ++j)
                g.u[j] = f2bf(Kb[(size_t)(ksg * 8 + j) * 1024 + n0c + knn]);
            *(bf16x8*)(Kbase + ksg * 1024 + knn * 16) = g.v;
        }
        // ---- stage V chunk: Vlds[s][nn], row stride 144B ----
        {
            const float4 a = *(const float4*)&Vb[(size_t)vs * 1024 + n0c + vng * 8];
            const float4 bq4 = *(const float4*)&Vb[(size_t)vs * 1024 + n0c + vng * 8 + 4];
            union { bf16x8 v; uint16_t u[8]; } g;
            g.u[0] = f2bf(a.x); g.u[1] = f2bf(a.y); g.u[2] = f2bf(a.z); g.u[3] = f2bf(a.w);
            g.u[4] = f2bf(bq4.x); g.u[5] = f2bf(bq4.y); g.u[6] = f2bf(bq4.z); g.u[7] = f2bf(bq4.w);
            *(bf16x8*)(Vbase + vs * 144 + vng * 16) = g.v;
        }
        __syncthreads();

        // ---- S phase: wave w owns n-subtile w (16 keys) x all 8 m-subtiles ----
        // A-frag: lane holds K[s = quad*8 + j][n = w*16 + c]
        const bf16x8 kf = *(const bf16x8*)(Kbase + quad * 1024 + (w * 16 + c) * 16);
        f32x4 sacc[8];
#pragma unroll
        for (int msub = 0; msub < 8; ++msub) {
            const f32x4 z = {0.f, 0.f, 0.f, 0.f};
            sacc[msub] = __builtin_amdgcn_mfma_f32_16x16x32_bf16(kf, qfrag[msub], z, 0, 0, 0);
        }
        // bias + exp + pack P (C-layout: col=c -> m, row=quad*4+r -> n)
        const int nb = n0c + w * 16 + quad * 4;
#pragma unroll
        for (int msub = 0; msub < 8; ++msub) {
            uint32_t pk[2];
            float ps[4];
#pragma unroll
            for (int r = 0; r < 4; ++r) {
                const int n  = nb + r;
                const int dy = (n >> 5) - my[msub] + 31;
                const int dx = (n & 31) - mx[msub] + 31;
                const float sc = sacc[msub][r] * 0.0625f + rbh[dy * 63 + dx];
                const float p  = __expf(sc);
                ps[r] = p;
                dsum[msub] += p;
            }
            pk[0] = (uint32_t)f2bf(ps[0]) | ((uint32_t)f2bf(ps[1]) << 16);
            pk[1] = (uint32_t)f2bf(ps[2]) | ((uint32_t)f2bf(ps[3]) << 16);
            // Plds[m = msub*16+c][n_in_chunk = w*16 + quad*4 .. +3]
            *(uint32_t*)(Pbase + (msub * 16 + c) * 144 + (w * 16 + quad * 4) * 2 + 0) = pk[0];
            *(uint32_t*)(Pbase + (msub * 16 + c) * 144 + (w * 16 + quad * 4) * 2 + 4) = pk[1];
        }
        __syncthreads();

        // ---- PV phase: wave w owns m-subtiles {2w, 2w+1}, both s-subtiles ----
#pragma unroll
        for (int kstep = 0; kstep < 2; ++kstep) {
            const bf16x8 vf0 = *(const bf16x8*)(Vbase + (0 * 16 + c) * 144 + kstep * 64 + quad * 16);
            const bf16x8 vf1 = *(const bf16x8*)(Vbase + (1 * 16 + c) * 144 + kstep * 64 + quad * 16);
#pragma unroll
            for (int mi = 0; mi < 2; ++mi) {
                const int msub = w * 2 + mi;
                const bf16x8 pf = *(const bf16x8*)(Pbase + (msub * 16 + c) * 144 + kstep * 64 + quad * 16);
                oacc[0][mi] = __builtin_amdgcn_mfma_f32_16x16x32_bf16(vf0, pf, oacc[0][mi], 0, 0, 0);
                oacc[1][mi] = __builtin_amdgcn_mfma_f32_16x16x32_bf16(vf1, pf, oacc[1][mi], 0, 0, 0);
            }
        }
    }

    // ---- denominator: reduce dsum over quads (shfl) then waves (LDS) ----
    __syncthreads();
#pragma unroll
    for (int msub = 0; msub < 8; ++msub) {
        float v = dsum[msub];
        v += __shfl_xor(v, 16, 64);
        v += __shfl_xor(v, 32, 64);
        if (quad == 0) red[w * 128 + msub * 16 + c] = v;
    }
    __syncthreads();

    float* Ob = O + base;
#pragma unroll
    for (int mi = 0; mi < 2; ++mi) {
        const int msub = w * 2 + mi;
        const float dtot = red[0 * 128 + msub * 16 + c] + red[1 * 128 + msub * 16 + c]
                         + red[2 * 128 + msub * 16 + c] + red[3 * 128 + msub * 16 + c];
        const float inv = 1.0f / dtot;
        const int m = m0 + msub * 16 + c;
#pragma unroll
        for (int ssub = 0; ssub < 2; ++ssub) {
#pragma unroll
            for (int r = 0; r < 4; ++r) {
                const int s = ssub * 16 + quad * 4 + r;
                Ob[(size_t)s * 1024 + m] = oacc[ssub][mi][r] * inv;
            }
        }
    }
}

// ---------------------------------------------------------------------------
// Kernel 4: output projection + bias + residual (unchanged from round 0).
// ---------------------------------------------------------------------------
__global__ __launch_bounds__(256) void oproj_kernel(
    const float* __restrict__ A, const float* __restrict__ wo,
    const float* __restrict__ bo, const float* __restrict__ x,
    float* __restrict__ out)
{
    __shared__ __align__(16) float As[16][68];
    __shared__ __align__(16) float Bs[16][68];
    const int blk = blockIdx.x;
    const int m0  = (blk >> 2) << 6;
    const int n0  = (blk & 3) << 6;
    const int tid = threadIdx.x;
    const int tm  = tid & 15, tn = tid >> 4;
    const int mi  = tid >> 2, ki = (tid & 3) << 2;

    float4 acc[4];
#pragma unroll
    for (int i = 0; i < 4; ++i) acc[i] = make_float4(0.f, 0.f, 0.f, 0.f);

    for (int kc = 0; kc < 16; ++kc) {
        const int k0 = kc << 4;
        const float4 a  = *(const float4*)&A [(size_t)(m0 + mi) * 256 + k0 + ki];
        const float4 w4 = *(const float4*)&wo[(size_t)(n0 + mi) * 256 + k0 + ki];
        __syncthreads();
        As[ki + 0][mi] = a.x;  As[ki + 1][mi] = a.y;
        As[ki + 2][mi] = a.z;  As[ki + 3][mi] = a.w;
        Bs[ki + 0][mi] = w4.x; Bs[ki + 1][mi] = w4.y;
        Bs[ki + 2][mi] = w4.z; Bs[ki + 3][mi] = w4.w;
        __syncthreads();
#pragma unroll
        for (int kk = 0; kk < 16; ++kk) {
            const float4 av = *(const float4*)&As[kk][tm << 2];
            const float4 b1 = *(const float4*)&Bs[kk][tn << 2];
            fma4(acc[0], av.x, b1);
            fma4(acc[1], av.y, b1);
            fma4(acc[2], av.z, b1);
            fma4(acc[3], av.w, b1);
        }
    }

    const int col = n0 + (tn << 2);
    const float4 bo4 = *(const float4*)&bo[col];
#pragma unroll
    for (int i = 0; i < 4; ++i) {
        const size_t row = (size_t)(m0 + (tm << 2) + i);
        const size_t g = row * 256 + col;
        const float4 r = *(const float4*)&x[g];
        float4 t = acc[i];
        t.x += bo4.x + r.x; t.y += bo4.y + r.y;
        t.z += bo4.z + r.z; t.w += bo4.w + r.w;
        *(float4*)&out[g] = t;
    }
}

// ---------------------------------------------------------------------------
extern "C" void kernel_launch(void* const* d_in, const int* in_sizes, int n_in,
                              void* d_out, int out_size, void* d_ws, size_t ws_size,
                              hipStream_t stream)
{
    (void)in_sizes; (void)n_in; (void)out_size; (void)ws_size;
    const float* x   = (const float*)d_in[0];
    const float* lng = (const float*)d_in[1];
    const float* lnb = (const float*)d_in[2];
    const float* wq  = (const float*)d_in[3];
    const float* bq  = (const float*)d_in[4];
    const float* wk  = (const float*)d_in[5];
    const float* bk  = (const float*)d_in[6];
    const float* wv  = (const float*)d_in[7];
    const float* bv  = (const float*)d_in[8];
    const float* wo  = (const float*)d_in[9];
    const float* bo  = (const float*)d_in[10];
    const float* rb  = (const float*)d_in[11];
    // d_in[12] (rel_idx) unused: index recomputed analytically in-kernel.

    float* ws = (float*)d_ws;                 // 5 * 16 MiB fp32 buffers
    float* X = ws;
    float* Q = ws + 1 * 4194304;
    float* K = ws + 2 * 4194304;
    float* V = ws + 3 * 4194304;
    float* O = ws + 4 * 4194304;
    float* out = (float*)d_out;

    hipLaunchKernelGGL(ln_kernel,    dim3(256),  dim3(256), 0, stream, x, lng, lnb, X);
    hipLaunchKernelGGL(qkv_kernel,   dim3(1024), dim3(256), 0, stream,
                       X, wq, bq, wk, bk, wv, bv, Q, K, V);
    hipLaunchKernelGGL(attn_kernel,  dim3(1024), dim3(256), 0, stream, Q, K, V, rb, O);
    hipLaunchKernelGGL(oproj_kernel, dim3(1024), dim3(256), 0, stream, O, wo, bo, x, out);
}

// Round 4
// 188.211 us; speedup vs baseline: 3.5218x; 1.4313x over previous
//
#include <hip/hip_runtime.h>
#include <cstdint>

#define PERB 262144   // C*H*H = N*D elements per batch

typedef __attribute__((ext_vector_type(8))) short bf16x8;
typedef __attribute__((ext_vector_type(4))) float f32x4;
typedef unsigned short ushort_t;

__device__ __forceinline__ uint16_t f2bf(float f) {
    uint32_t u = __float_as_uint(f);
    u += 0x7fff + ((u >> 16) & 1);   // RNE
    return (uint16_t)(u >> 16);
}

// ---------------------------------------------------------------------------
// Kernel 0: convert the 4 weight matrices (256x256 fp32) to bf16.
// grid 256 = 4 weights x 64 blocks; 256 thr x 4 elems.
// ---------------------------------------------------------------------------
__global__ __launch_bounds__(256) void wcvt_kernel(
    const float* __restrict__ wq, const float* __restrict__ wk,
    const float* __restrict__ wv, const float* __restrict__ wo,
    ushort_t* __restrict__ oq, ushort_t* __restrict__ ok,
    ushort_t* __restrict__ ov, ushort_t* __restrict__ oo)
{
    const int which = blockIdx.x >> 6;
    const int idx = ((blockIdx.x & 63) * 256 + threadIdx.x) * 4;
    const float* src = which == 0 ? wq : which == 1 ? wk : which == 2 ? wv : wo;
    ushort_t* dst    = which == 0 ? oq : which == 1 ? ok : which == 2 ? ov : oo;
    const float4 v = *(const float4*)&src[idx];
    uint2 p;
    p.x = (uint32_t)f2bf(v.x) | ((uint32_t)f2bf(v.y) << 16);
    p.y = (uint32_t)f2bf(v.z) | ((uint32_t)f2bf(v.w) << 16);
    *(uint2*)&dst[idx] = p;
}

// ---------------------------------------------------------------------------
// Kernel 1: LayerNorm over channel axis; output bf16 (same flat layout).
// ---------------------------------------------------------------------------
__global__ __launch_bounds__(256) void ln_kernel(
    const float* __restrict__ x, const float* __restrict__ gam,
    const float* __restrict__ bet, ushort_t* __restrict__ X)
{
    const int blk = blockIdx.x;
    const int b   = blk >> 4;
    const int sp0 = (blk & 15) << 6;
    const int tid = threadIdx.x;
    const int spl = tid & 63;
    const int cg  = tid >> 6;
    const int c0  = cg << 6;
    const int sp  = sp0 + spl;
    const float* xb = x + (size_t)b * PERB + sp;

    float vals[64];
    float s = 0.f, sq = 0.f;
#pragma unroll
    for (int i = 0; i < 64; ++i) {
        float v = xb[(size_t)(c0 + i) * 1024];
        vals[i] = v; s += v; sq += v * v;
    }
    __shared__ float rs[4][64];
    __shared__ float rq[4][64];
    rs[cg][spl] = s; rq[cg][spl] = sq;
    __syncthreads();
    const float ts = rs[0][spl] + rs[1][spl] + rs[2][spl] + rs[3][spl];
    const float tq = rq[0][spl] + rq[1][spl] + rq[2][spl] + rq[3][spl];
    const float mean = ts * (1.f / 256.f);
    const float var  = tq * (1.f / 256.f) - mean * mean;
    const float rstd = rsqrtf(var + 1e-5f);

    ushort_t* Xb = X + (size_t)b * PERB + sp;
#pragma unroll
    for (int i = 0; i < 64; ++i) {
        const int c = c0 + i;
        Xb[(size_t)c * 1024] = f2bf((vals[i] - mean) * rstd * gam[c] + bet[c]);
    }
}

// ---------------------------------------------------------------------------
// Kernel 2: MFMA fused Q/K/V projection (bf16 in, bf16 out).
// out[m,n] = sum_k X[m,k]*W[n,k] + b[n].  Mtile=64, Ntile=64, k-chunks of 64.
// Granule layout: 16B = 8 consecutive k for one row. Wave w owns nsub w.
// mfma(Wfrag, Xfrag) -> lane(c,quad) reg r = out[msub*16+c][n0+w*16+quad*4+r].
// Grid: 256 mtiles x 4 ntiles = 1024 blocks.
// ---------------------------------------------------------------------------
__global__ __launch_bounds__(256, 3) void qkv_kernel(
    const ushort_t* __restrict__ X,
    const ushort_t* __restrict__ wq, const float* __restrict__ bq,
    const ushort_t* __restrict__ wk, const float* __restrict__ bk,
    const ushort_t* __restrict__ wv, const float* __restrict__ bv,
    ushort_t* __restrict__ Q, ushort_t* __restrict__ K, ushort_t* __restrict__ V)
{
    __shared__ __align__(16) ushort_t Xl[512 * 8];     // granule (kq,m): (kq*64+m)*8
    __shared__ __align__(16) ushort_t Wl[3][512 * 8];  // granule (kq,n): (kq*64+n)*8

    const int blk = blockIdx.x;
    const int m0  = (blk >> 2) << 6;
    const int n0  = (blk & 3) << 6;
    const int tid = threadIdx.x;
    const int w    = tid >> 6;
    const int lane = tid & 63;
    const int quad = lane >> 4;
    const int c    = lane & 15;

    f32x4 acc[3][4];
#pragma unroll
    for (int o3 = 0; o3 < 3; ++o3)
#pragma unroll
        for (int i = 0; i < 4; ++i) acc[o3][i] = (f32x4){0.f, 0.f, 0.f, 0.f};

    for (int kc = 0; kc < 4; ++kc) {
        const int k0 = kc << 6;
        __syncthreads();
        // stage X chunk: 512 granules (kq 0..7, m 0..63), 2 per thread
#pragma unroll
        for (int i = 0; i < 2; ++i) {
            const int id = tid + i * 256;
            const int kq = id >> 6, m = id & 63;
            *(bf16x8*)&Xl[id * 8] = *(const bf16x8*)&X[(size_t)(m0 + m) * 256 + k0 + kq * 8];
        }
        // stage W chunks: 512 granules each, 2 per thread per W
#pragma unroll
        for (int i = 0; i < 2; ++i) {
            const int id = tid + i * 256;
            const int kq = id >> 6, n = id & 63;
            const size_t g = (size_t)(n0 + n) * 256 + k0 + kq * 8;
            *(bf16x8*)&Wl[0][id * 8] = *(const bf16x8*)&wq[g];
            *(bf16x8*)&Wl[1][id * 8] = *(const bf16x8*)&wk[g];
            *(bf16x8*)&Wl[2][id * 8] = *(const bf16x8*)&wv[g];
        }
        __syncthreads();
#pragma unroll
        for (int ks = 0; ks < 2; ++ks) {
            const int kq = ks * 4 + quad;
            bf16x8 af[4];
#pragma unroll
            for (int msub = 0; msub < 4; ++msub)
                af[msub] = *(const bf16x8*)&Xl[(kq * 64 + msub * 16 + c) * 8];
            bf16x8 bw[3];
#pragma unroll
            for (int o3 = 0; o3 < 3; ++o3)
                bw[o3] = *(const bf16x8*)&Wl[o3][(kq * 64 + w * 16 + c) * 8];
#pragma unroll
            for (int o3 = 0; o3 < 3; ++o3)
#pragma unroll
                for (int msub = 0; msub < 4; ++msub)
                    acc[o3][msub] = __builtin_amdgcn_mfma_f32_16x16x32_bf16(
                        bw[o3], af[msub], acc[o3][msub], 0, 0, 0);
        }
    }

    const int n = n0 + w * 16 + quad * 4;
    const float4 bq4 = *(const float4*)&bq[n];
    const float4 bk4 = *(const float4*)&bk[n];
    const float4 bv4 = *(const float4*)&bv[n];
    ushort_t* outs[3] = {Q, K, V};
    const float4 bias[3] = {bq4, bk4, bv4};
#pragma unroll
    for (int msub = 0; msub < 4; ++msub) {
        const size_t m = (size_t)(m0 + msub * 16 + c);
#pragma unroll
        for (int o3 = 0; o3 < 3; ++o3) {
            const f32x4 a = acc[o3][msub];
            uint2 p;
            p.x = (uint32_t)f2bf(a[0] + bias[o3].x) | ((uint32_t)f2bf(a[1] + bias[o3].y) << 16);
            p.y = (uint32_t)f2bf(a[2] + bias[o3].z) | ((uint32_t)f2bf(a[3] + bias[o3].w) << 16);
            *(uint2*)&outs[o3][m * 256 + n] = p;
        }
    }
}

// ---------------------------------------------------------------------------
// Kernel 3: MFMA flash attention (bf16 Q/K/V in, bf16 O out).
// ---------------------------------------------------------------------------
__global__ __launch_bounds__(256, 3) void attn_kernel(
    const ushort_t* __restrict__ Q, const ushort_t* __restrict__ K,
    const ushort_t* __restrict__ V, const float* __restrict__ relb,
    ushort_t* __restrict__ O)
{
    __shared__ __align__(16) unsigned char smem[29184];
    char* Pbase = (char*)smem;
    char* Kbase = (char*)smem + 18432;
    char* Vbase = (char*)smem + 22528;
    float* red  = (float*)(smem + 27136);

    const int blk = blockIdx.x;
    const int bh  = blk & 127;
    const int mt  = blk >> 7;
    const int b   = bh >> 3;
    const int h   = bh & 7;
    const int m0  = mt << 7;
    const int tid = threadIdx.x;
    const int w    = tid >> 6;
    const int lane = tid & 63;
    const int quad = lane >> 4;
    const int c    = lane & 15;

    const size_t base = (size_t)b * PERB + (size_t)h * 32768;
    const ushort_t* Qb = Q + base;
    const ushort_t* Kb = K + base;
    const ushort_t* Vb = V + base;
    const float* rbh = relb + h * 3969;

    // ---- stage Q [32s x 128m] -> Qlds (in Pbase region), granule layout ----
    {
        const int mm = tid & 127;
        const int sg = tid >> 7;
        union { bf16x8 v; uint16_t u[8]; } g0, g1;
#pragma unroll
        for (int j = 0; j < 8; ++j)
            g0.u[j] = Qb[(size_t)(sg * 16 + j) * 1024 + m0 + mm];
#pragma unroll
        for (int j = 0; j < 8; ++j)
            g1.u[j] = Qb[(size_t)(sg * 16 + 8 + j) * 1024 + m0 + mm];
        *(bf16x8*)(Pbase + (sg * 2 + 0) * 2048 + mm * 16) = g0.v;
        *(bf16x8*)(Pbase + (sg * 2 + 1) * 2048 + mm * 16) = g1.v;
    }
    __syncthreads();
    bf16x8 qfrag[8];
#pragma unroll
    for (int msub = 0; msub < 8; ++msub)
        qfrag[msub] = *(const bf16x8*)(Pbase + quad * 2048 + (msub * 16 + c) * 16);

    int my[8], mx[8];
#pragma unroll
    for (int msub = 0; msub < 8; ++msub) {
        const int m = m0 + msub * 16 + c;
        my[msub] = m >> 5; mx[msub] = m & 31;
    }

    f32x4 oacc[2][2];
#pragma unroll
    for (int i = 0; i < 2; ++i)
#pragma unroll
        for (int j = 0; j < 2; ++j)
            oacc[i][j] = (f32x4){0.f, 0.f, 0.f, 0.f};
    float dsum[8];
#pragma unroll
    for (int i = 0; i < 8; ++i) dsum[i] = 0.f;

    const int knn = tid & 63, ksg = (tid >> 6) & 3;
    const int vs = tid >> 3, vng = tid & 7;

    for (int ch = 0; ch < 16; ++ch) {
        const int n0c = ch << 6;
        __syncthreads();

        // stage K chunk (column gather, 8 ushort loads -> 1 b128 write)
        {
            union { bf16x8 v; uint16_t u[8]; } g;
#pragma unroll
            for (int j = 0; j < 8; ++j)
                g.u[j] = Kb[(size_t)(ksg * 8 + j) * 1024 + n0c + knn];
            *(bf16x8*)(Kbase + ksg * 1024 + knn * 16) = g.v;
        }
        // stage V chunk (direct 16B copy)
        *(bf16x8*)(Vbase + vs * 144 + vng * 16) =
            *(const bf16x8*)&Vb[(size_t)vs * 1024 + n0c + vng * 8];
        __syncthreads();

        const bf16x8 kf = *(const bf16x8*)(Kbase + quad * 1024 + (w * 16 + c) * 16);
        f32x4 sacc[8];
#pragma unroll
        for (int msub = 0; msub < 8; ++msub) {
            const f32x4 z = {0.f, 0.f, 0.f, 0.f};
            sacc[msub] = __builtin_amdgcn_mfma_f32_16x16x32_bf16(kf, qfrag[msub], z, 0, 0, 0);
        }
        const int nb = n0c + w * 16 + quad * 4;
#pragma unroll
        for (int msub = 0; msub < 8; ++msub) {
            uint32_t pk[2];
            float ps[4];
#pragma unroll
            for (int r = 0; r < 4; ++r) {
                const int n  = nb + r;
                const int dy = (n >> 5) - my[msub] + 31;
                const int dx = (n & 31) - mx[msub] + 31;
                const float sc = sacc[msub][r] * 0.0625f + rbh[dy * 63 + dx];
                const float p  = __expf(sc);
                ps[r] = p;
                dsum[msub] += p;
            }
            pk[0] = (uint32_t)f2bf(ps[0]) | ((uint32_t)f2bf(ps[1]) << 16);
            pk[1] = (uint32_t)f2bf(ps[2]) | ((uint32_t)f2bf(ps[3]) << 16);
            *(uint32_t*)(Pbase + (msub * 16 + c) * 144 + (w * 16 + quad * 4) * 2 + 0) = pk[0];
            *(uint32_t*)(Pbase + (msub * 16 + c) * 144 + (w * 16 + quad * 4) * 2 + 4) = pk[1];
        }
        __syncthreads();

#pragma unroll
        for (int kstep = 0; kstep < 2; ++kstep) {
            const bf16x8 vf0 = *(const bf16x8*)(Vbase + (0 * 16 + c) * 144 + kstep * 64 + quad * 16);
            const bf16x8 vf1 = *(const bf16x8*)(Vbase + (1 * 16 + c) * 144 + kstep * 64 + quad * 16);
#pragma unroll
            for (int mi = 0; mi < 2; ++mi) {
                const int msub = w * 2 + mi;
                const bf16x8 pf = *(const bf16x8*)(Pbase + (msub * 16 + c) * 144 + kstep * 64 + quad * 16);
                oacc[0][mi] = __builtin_amdgcn_mfma_f32_16x16x32_bf16(vf0, pf, oacc[0][mi], 0, 0, 0);
                oacc[1][mi] = __builtin_amdgcn_mfma_f32_16x16x32_bf16(vf1, pf, oacc[1][mi], 0, 0, 0);
            }
        }
    }

    __syncthreads();
#pragma unroll
    for (int msub = 0; msub < 8; ++msub) {
        float v = dsum[msub];
        v += __shfl_xor(v, 16, 64);
        v += __shfl_xor(v, 32, 64);
        if (quad == 0) red[w * 128 + msub * 16 + c] = v;
    }
    __syncthreads();

    ushort_t* Ob = O + base;
#pragma unroll
    for (int mi = 0; mi < 2; ++mi) {
        const int msub = w * 2 + mi;
        const float dtot = red[0 * 128 + msub * 16 + c] + red[1 * 128 + msub * 16 + c]
                         + red[2 * 128 + msub * 16 + c] + red[3 * 128 + msub * 16 + c];
        const float inv = 1.0f / dtot;
        const int m = m0 + msub * 16 + c;
#pragma unroll
        for (int ssub = 0; ssub < 2; ++ssub) {
#pragma unroll
            for (int r = 0; r < 4; ++r) {
                const int s = ssub * 16 + quad * 4 + r;
                Ob[(size_t)s * 1024 + m] = f2bf(oacc[ssub][mi][r] * inv);
            }
        }
    }
}

// ---------------------------------------------------------------------------
// Kernel 4: MFMA output projection + bias + residual (bf16 A/W, fp32 out).
// Mtile=64, Ntile=64, grid 1024.
// ---------------------------------------------------------------------------
__global__ __launch_bounds__(256, 4) void oproj_kernel(
    const ushort_t* __restrict__ A, const ushort_t* __restrict__ wo,
    const float* __restrict__ bo, const float* __restrict__ x,
    float* __restrict__ out)
{
    __shared__ __align__(16) ushort_t Al[512 * 8];
    __shared__ __align__(16) ushort_t Wl[512 * 8];

    const int blk = blockIdx.x;
    const int m0  = (blk >> 2) << 6;
    const int n0  = (blk & 3) << 6;
    const int tid = threadIdx.x;
    const int w    = tid >> 6;
    const int lane = tid & 63;
    const int quad = lane >> 4;
    const int c    = lane & 15;

    f32x4 acc[4];
#pragma unroll
    for (int i = 0; i < 4; ++i) acc[i] = (f32x4){0.f, 0.f, 0.f, 0.f};

    for (int kc = 0; kc < 4; ++kc) {
        const int k0 = kc << 6;
        __syncthreads();
#pragma unroll
        for (int i = 0; i < 2; ++i) {
            const int id = tid + i * 256;
            const int kq = id >> 6, mn = id & 63;
            *(bf16x8*)&Al[id * 8] = *(const bf16x8*)&A [(size_t)(m0 + mn) * 256 + k0 + kq * 8];
            *(bf16x8*)&Wl[id * 8] = *(const bf16x8*)&wo[(size_t)(n0 + mn) * 256 + k0 + kq * 8];
        }
        __syncthreads();
#pragma unroll
        for (int ks = 0; ks < 2; ++ks) {
            const int kq = ks * 4 + quad;
            const bf16x8 bw = *(const bf16x8*)&Wl[(kq * 64 + w * 16 + c) * 8];
#pragma unroll
            for (int msub = 0; msub < 4; ++msub) {
                const bf16x8 af = *(const bf16x8*)&Al[(kq * 64 + msub * 16 + c) * 8];
                acc[msub] = __builtin_amdgcn_mfma_f32_16x16x32_bf16(bw, af, acc[msub], 0, 0, 0);
            }
        }
    }

    const int n = n0 + w * 16 + quad * 4;
    const float4 bo4 = *(const float4*)&bo[n];
#pragma unroll
    for (int msub = 0; msub < 4; ++msub) {
        const size_t g = (size_t)(m0 + msub * 16 + c) * 256 + n;
        const float4 r = *(const float4*)&x[g];
        float4 t;
        t.x = acc[msub][0] + bo4.x + r.x;
        t.y = acc[msub][1] + bo4.y + r.y;
        t.z = acc[msub][2] + bo4.z + r.z;
        t.w = acc[msub][3] + bo4.w + r.w;
        *(float4*)&out[g] = t;
    }
}

// ---------------------------------------------------------------------------
extern "C" void kernel_launch(void* const* d_in, const int* in_sizes, int n_in,
                              void* d_out, int out_size, void* d_ws, size_t ws_size,
                              hipStream_t stream)
{
    (void)in_sizes; (void)n_in; (void)out_size; (void)ws_size;
    const float* x   = (const float*)d_in[0];
    const float* lng = (const float*)d_in[1];
    const float* lnb = (const float*)d_in[2];
    const float* wq  = (const float*)d_in[3];
    const float* bq  = (const float*)d_in[4];
    const float* wk  = (const float*)d_in[5];
    const float* bk  = (const float*)d_in[6];
    const float* wv  = (const float*)d_in[7];
    const float* bv  = (const float*)d_in[8];
    const float* wo  = (const float*)d_in[9];
    const float* bo  = (const float*)d_in[10];
    const float* rb  = (const float*)d_in[11];
    // d_in[12] (rel_idx) unused: index recomputed analytically in-kernel.

    ushort_t* ws = (ushort_t*)d_ws;
    ushort_t* Xbf = ws;                       // 4194304 elems each
    ushort_t* Qbf = ws + 1 * 4194304;
    ushort_t* Kbf = ws + 2 * 4194304;
    ushort_t* Vbf = ws + 3 * 4194304;
    ushort_t* Obf = ws + 4 * 4194304;
    ushort_t* Wqb = ws + 5 * 4194304;
    ushort_t* Wkb = Wqb + 65536;
    ushort_t* Wvb = Wkb + 65536;
    ushort_t* Wob = Wvb + 65536;
    float* out = (float*)d_out;

    hipLaunchKernelGGL(wcvt_kernel,  dim3(256),  dim3(256), 0, stream,
                       wq, wk, wv, wo, Wqb, Wkb, Wvb, Wob);
    hipLaunchKernelGGL(ln_kernel,    dim3(256),  dim3(256), 0, stream, x, lng, lnb, Xbf);
    hipLaunchKernelGGL(qkv_kernel,   dim3(1024), dim3(256), 0, stream,
                       Xbf, Wqb, bq, Wkb, bk, Wvb, bv, Qbf, Kbf, Vbf);
    hipLaunchKernelGGL(attn_kernel,  dim3(1024), dim3(256), 0, stream, Qbf, Kbf, Vbf, rb, Obf);
    hipLaunchKernelGGL(oproj_kernel, dim3(1024), dim3(256), 0, stream, Obf, Wob, bo, x, out);
}

// Round 5
// 180.190 us; speedup vs baseline: 3.6786x; 1.0445x over previous
//
#include <hip/hip_runtime.h>
#include <cstdint>

#define PERB 262144   // C*H*H = N*D elements per batch

typedef __attribute__((ext_vector_type(8))) short bf16x8;
typedef __attribute__((ext_vector_type(4))) float f32x4;
typedef unsigned short ushort_t;

__device__ __forceinline__ uint16_t f2bf(float f) {
    uint32_t u = __float_as_uint(f);
    u += 0x7fff + ((u >> 16) & 1);   // RNE
    return (uint16_t)(u >> 16);
}

// ---------------------------------------------------------------------------
// Kernel 0: convert the 4 weight matrices (256x256 fp32) to bf16.
// ---------------------------------------------------------------------------
__global__ __launch_bounds__(256) void wcvt_kernel(
    const float* __restrict__ wq, const float* __restrict__ wk,
    const float* __restrict__ wv, const float* __restrict__ wo,
    ushort_t* __restrict__ oq, ushort_t* __restrict__ ok,
    ushort_t* __restrict__ ov, ushort_t* __restrict__ oo)
{
    const int which = blockIdx.x >> 6;
    const int idx = ((blockIdx.x & 63) * 256 + threadIdx.x) * 4;
    const float* src = which == 0 ? wq : which == 1 ? wk : which == 2 ? wv : wo;
    ushort_t* dst    = which == 0 ? oq : which == 1 ? ok : which == 2 ? ov : oo;
    const float4 v = *(const float4*)&src[idx];
    uint2 p;
    p.x = (uint32_t)f2bf(v.x) | ((uint32_t)f2bf(v.y) << 16);
    p.y = (uint32_t)f2bf(v.z) | ((uint32_t)f2bf(v.w) << 16);
    *(uint2*)&dst[idx] = p;
}

// ---------------------------------------------------------------------------
// Kernel 1: LayerNorm over channel axis; output bf16 (same flat layout).
// ---------------------------------------------------------------------------
__global__ __launch_bounds__(256) void ln_kernel(
    const float* __restrict__ x, const float* __restrict__ gam,
    const float* __restrict__ bet, ushort_t* __restrict__ X)
{
    const int blk = blockIdx.x;
    const int b   = blk >> 4;
    const int sp0 = (blk & 15) << 6;
    const int tid = threadIdx.x;
    const int spl = tid & 63;
    const int cg  = tid >> 6;
    const int c0  = cg << 6;
    const int sp  = sp0 + spl;
    const float* xb = x + (size_t)b * PERB + sp;

    float vals[64];
    float s = 0.f, sq = 0.f;
#pragma unroll
    for (int i = 0; i < 64; ++i) {
        float v = xb[(size_t)(c0 + i) * 1024];
        vals[i] = v; s += v; sq += v * v;
    }
    __shared__ float rs[4][64];
    __shared__ float rq[4][64];
    rs[cg][spl] = s; rq[cg][spl] = sq;
    __syncthreads();
    const float ts = rs[0][spl] + rs[1][spl] + rs[2][spl] + rs[3][spl];
    const float tq = rq[0][spl] + rq[1][spl] + rq[2][spl] + rq[3][spl];
    const float mean = ts * (1.f / 256.f);
    const float var  = tq * (1.f / 256.f) - mean * mean;
    const float rstd = rsqrtf(var + 1e-5f);

    ushort_t* Xb = X + (size_t)b * PERB + sp;
#pragma unroll
    for (int i = 0; i < 64; ++i) {
        const int c = c0 + i;
        Xb[(size_t)c * 1024] = f2bf((vals[i] - mean) * rstd * gam[c] + bet[c]);
    }
}

// ---------------------------------------------------------------------------
// Kernel 2: MFMA fused Q/K/V projection (bf16 in, bf16 out). Unchanged.
// ---------------------------------------------------------------------------
__global__ __launch_bounds__(256, 3) void qkv_kernel(
    const ushort_t* __restrict__ X,
    const ushort_t* __restrict__ wq, const float* __restrict__ bq,
    const ushort_t* __restrict__ wk, const float* __restrict__ bk,
    const ushort_t* __restrict__ wv, const float* __restrict__ bv,
    ushort_t* __restrict__ Q, ushort_t* __restrict__ K, ushort_t* __restrict__ V)
{
    __shared__ __align__(16) ushort_t Xl[512 * 8];
    __shared__ __align__(16) ushort_t Wl[3][512 * 8];

    const int blk = blockIdx.x;
    const int m0  = (blk >> 2) << 6;
    const int n0  = (blk & 3) << 6;
    const int tid = threadIdx.x;
    const int w    = tid >> 6;
    const int lane = tid & 63;
    const int quad = lane >> 4;
    const int c    = lane & 15;

    f32x4 acc[3][4];
#pragma unroll
    for (int o3 = 0; o3 < 3; ++o3)
#pragma unroll
        for (int i = 0; i < 4; ++i) acc[o3][i] = (f32x4){0.f, 0.f, 0.f, 0.f};

    for (int kc = 0; kc < 4; ++kc) {
        const int k0 = kc << 6;
        __syncthreads();
#pragma unroll
        for (int i = 0; i < 2; ++i) {
            const int id = tid + i * 256;
            const int kq = id >> 6, m = id & 63;
            *(bf16x8*)&Xl[id * 8] = *(const bf16x8*)&X[(size_t)(m0 + m) * 256 + k0 + kq * 8];
        }
#pragma unroll
        for (int i = 0; i < 2; ++i) {
            const int id = tid + i * 256;
            const int kq = id >> 6, n = id & 63;
            const size_t g = (size_t)(n0 + n) * 256 + k0 + kq * 8;
            *(bf16x8*)&Wl[0][id * 8] = *(const bf16x8*)&wq[g];
            *(bf16x8*)&Wl[1][id * 8] = *(const bf16x8*)&wk[g];
            *(bf16x8*)&Wl[2][id * 8] = *(const bf16x8*)&wv[g];
        }
        __syncthreads();
#pragma unroll
        for (int ks = 0; ks < 2; ++ks) {
            const int kq = ks * 4 + quad;
            bf16x8 af[4];
#pragma unroll
            for (int msub = 0; msub < 4; ++msub)
                af[msub] = *(const bf16x8*)&Xl[(kq * 64 + msub * 16 + c) * 8];
            bf16x8 bw[3];
#pragma unroll
            for (int o3 = 0; o3 < 3; ++o3)
                bw[o3] = *(const bf16x8*)&Wl[o3][(kq * 64 + w * 16 + c) * 8];
#pragma unroll
            for (int o3 = 0; o3 < 3; ++o3)
#pragma unroll
                for (int msub = 0; msub < 4; ++msub)
                    acc[o3][msub] = __builtin_amdgcn_mfma_f32_16x16x32_bf16(
                        bw[o3], af[msub], acc[o3][msub], 0, 0, 0);
        }
    }

    const int n = n0 + w * 16 + quad * 4;
    const float4 bq4 = *(const float4*)&bq[n];
    const float4 bk4 = *(const float4*)&bk[n];
    const float4 bv4 = *(const float4*)&bv[n];
    ushort_t* outs[3] = {Q, K, V};
    const float4 bias[3] = {bq4, bk4, bv4};
#pragma unroll
    for (int msub = 0; msub < 4; ++msub) {
        const size_t m = (size_t)(m0 + msub * 16 + c);
#pragma unroll
        for (int o3 = 0; o3 < 3; ++o3) {
            const f32x4 a = acc[o3][msub];
            uint2 p;
            p.x = (uint32_t)f2bf(a[0] + bias[o3].x) | ((uint32_t)f2bf(a[1] + bias[o3].y) << 16);
            p.y = (uint32_t)f2bf(a[2] + bias[o3].z) | ((uint32_t)f2bf(a[3] + bias[o3].w) << 16);
            *(uint2*)&outs[o3][m * 256 + n] = p;
        }
    }
}

// ---------------------------------------------------------------------------
// Kernel 3: MFMA flash attention, round-5 rewrite.
//  - bias*log2e staged in LDS; score idx = noff(n) + moff(m), hoisted
//  - p = exp2(sacc*C1 + blog) via v_exp_f32
//  - trunc-bf16 P pack via v_perm
//  - denominator via mfma(ones, pf) -> no reductions
//  - XOR-swizzled 128B-row P/V (conflict-free minimum), V double-buffered
//  - register prefetch of next chunk's K/V; 2 barriers per chunk
// ---------------------------------------------------------------------------
#define C1F 0.09016844005556022f   // 0.0625 * log2(e)
#define LOG2EF 1.4426950408889634f

__global__ __launch_bounds__(256, 3) void attn_kernel(
    const ushort_t* __restrict__ Q, const ushort_t* __restrict__ K,
    const ushort_t* __restrict__ V, const float* __restrict__ relb,
    ushort_t* __restrict__ O)
{
    // LDS map (bytes):
    //   [0, 15888)        blog: 3969 f32 = bias * log2e
    //   [15888, 32272)    P: 128 rows x 128B, 16B-unit swizzle ^(m&7); Q staging at start
    //   [32272, 36368)    K: granule (q=s>>3)*1024 + nn*16
    //   [36368, 44560)    V dbuf: buf*4096 + s*128, 16B-unit swizzle ^(s&7)
    __shared__ __align__(16) unsigned char smem[44560];
    float* blog = (float*)smem;
    char*  Pb   = (char*)(smem + 15888);
    char*  Kl   = (char*)(smem + 32272);
    char*  Vl   = (char*)(smem + 36368);

    const int blk = blockIdx.x;
    const int bh  = blk & 127;
    const int mt  = blk >> 7;
    const int b   = bh >> 3;
    const int h   = bh & 7;
    const int m0  = mt << 7;
    const int tid = threadIdx.x;
    const int w    = tid >> 6;
    const int lane = tid & 63;
    const int quad = lane >> 4;
    const int c    = lane & 15;

    const size_t base = (size_t)b * PERB + (size_t)h * 32768;
    const ushort_t* Qg = Q + base;
    const ushort_t* Kg = K + base;
    const ushort_t* Vg = V + base;
    const float* rbh = relb + h * 3969;

    // ---- stage blog = bias*log2e ----
    for (int i = tid; i < 3969; i += 256) blog[i] = rbh[i] * LOG2EF;

    // ---- stage Q [32s x 128m] into Pb (granule layout), then read frags ----
    {
        const int mm = tid & 127;
        const int sg = tid >> 7;
        union { bf16x8 v; uint16_t u[8]; } g0, g1;
#pragma unroll
        for (int j = 0; j < 8; ++j)
            g0.u[j] = Qg[(size_t)(sg * 16 + j) * 1024 + m0 + mm];
#pragma unroll
        for (int j = 0; j < 8; ++j)
            g1.u[j] = Qg[(size_t)(sg * 16 + 8 + j) * 1024 + m0 + mm];
        *(bf16x8*)(Pb + (sg * 2 + 0) * 2048 + mm * 16) = g0.v;
        *(bf16x8*)(Pb + (sg * 2 + 1) * 2048 + mm * 16) = g1.v;
    }
    __syncthreads();
    bf16x8 qfrag[8];
#pragma unroll
    for (int msub = 0; msub < 8; ++msub)
        qfrag[msub] = *(const bf16x8*)(Pb + quad * 2048 + (msub * 16 + c) * 16);

    // per-msub bias m-offset: idx = noff(n) + moff(m)
    int moff[8];
#pragma unroll
    for (int msub = 0; msub < 8; ++msub) {
        const int m = m0 + msub * 16 + c;
        moff[msub] = 1984 - (m >> 5) * 63 - (m & 31);
    }

    // accumulators
    f32x4 oacc[2][2], dacc[2];
#pragma unroll
    for (int i = 0; i < 2; ++i) {
        dacc[i] = (f32x4){0.f, 0.f, 0.f, 0.f};
#pragma unroll
        for (int j = 0; j < 2; ++j) oacc[i][j] = (f32x4){0.f, 0.f, 0.f, 0.f};
    }
    bf16x8 onesf;
#pragma unroll
    for (int j = 0; j < 8; ++j) onesf[j] = (short)0x3F80;

    // staging thread coords + hoisted LDS addresses
    const int knn = tid & 63, ksg = tid >> 6;   // K: 8 s-values for column knn
    const int vs  = tid >> 3, vng = tid & 7;    // V: unit16 vng of row vs
    const int kWr = ksg * 1024 + knn * 16;
    const int vWr = vs * 128 + ((vng ^ (vs & 7)) << 4);
    const int kRd = quad * 1024 + (w * 16 + c) * 16;
    const int pWr = c * 128 + (((2 * w + (quad >> 1)) ^ (c & 7)) << 4) + ((quad & 1) << 3);
    const int c7  = c & 7;

    // prologue: prefetch chunk 0
    uint32_t kpre[8]; bf16x8 vpre;
#pragma unroll
    for (int j = 0; j < 8; ++j) kpre[j] = Kg[(size_t)(ksg * 8 + j) * 1024 + knn];
    vpre = *(const bf16x8*)&Vg[(size_t)vs * 1024 + vng * 8];

    for (int ch = 0; ch < 16; ++ch) {
        const int n0c = ch << 6;
        const int cb  = ch & 1;

        // ---- write prefetched K/V to LDS ----
        {
            uint4 kp;
            kp.x = kpre[0] | (kpre[1] << 16);
            kp.y = kpre[2] | (kpre[3] << 16);
            kp.z = kpre[4] | (kpre[5] << 16);
            kp.w = kpre[6] | (kpre[7] << 16);
            *(uint4*)(Kl + kWr) = kp;
            *(bf16x8*)(Vl + cb * 4096 + vWr) = vpre;
        }
        __syncthreads();   // staging visible; prev PV done for all waves

        // ---- prefetch next chunk into regs (overlaps S phase) ----
        {
            const int n0n = ((ch + 1) & 15) << 6;
#pragma unroll
            for (int j = 0; j < 8; ++j)
                kpre[j] = Kg[(size_t)(ksg * 8 + j) * 1024 + n0n + knn];
            vpre = *(const bf16x8*)&Vg[(size_t)vs * 1024 + n0n + vng * 8];
        }

        // ---- S phase ----
        const bf16x8 kf = *(const bf16x8*)(Kl + kRd);
        f32x4 sacc[8];
#pragma unroll
        for (int msub = 0; msub < 8; ++msub) {
            const f32x4 z = {0.f, 0.f, 0.f, 0.f};
            sacc[msub] = __builtin_amdgcn_mfma_f32_16x16x32_bf16(kf, qfrag[msub], z, 0, 0, 0);
        }

        // ---- bias + exp2 + trunc-pack + P write ----
        const int nbase = n0c + w * 16 + quad * 4;
        int nidx[4];
#pragma unroll
        for (int r = 0; r < 4; ++r) {
            const int n = nbase + r;
            nidx[r] = (n >> 5) * 63 + (n & 31);
        }
#pragma unroll
        for (int msub = 0; msub < 8; ++msub) {
            const int mo = moff[msub];
            float p[4];
#pragma unroll
            for (int r = 0; r < 4; ++r)
                p[r] = __builtin_amdgcn_exp2f(fmaf(sacc[msub][r], C1F, blog[nidx[r] + mo]));
            uint2 pk;
            pk.x = __builtin_amdgcn_perm(__float_as_uint(p[1]), __float_as_uint(p[0]), 0x07060302u);
            pk.y = __builtin_amdgcn_perm(__float_as_uint(p[3]), __float_as_uint(p[2]), 0x07060302u);
            *(uint2*)(Pb + msub * 2048 + pWr) = pk;
        }
        __syncthreads();   // P (and V) ready for PV

        // ---- PV phase: wave w owns msub {2w, 2w+1} ----
#pragma unroll
        for (int kstep = 0; kstep < 2; ++kstep) {
            const int u = ((kstep * 4 + quad) ^ c7) << 4;
            const bf16x8 vf0 = *(const bf16x8*)(Vl + cb * 4096 + c * 128 + u);
            const bf16x8 vf1 = *(const bf16x8*)(Vl + cb * 4096 + (16 + c) * 128 + u);
#pragma unroll
            for (int mi = 0; mi < 2; ++mi) {
                const bf16x8 pf = *(const bf16x8*)(Pb + ((w * 2 + mi) * 16 + c) * 128 + u);
                oacc[0][mi] = __builtin_amdgcn_mfma_f32_16x16x32_bf16(vf0, pf, oacc[0][mi], 0, 0, 0);
                oacc[1][mi] = __builtin_amdgcn_mfma_f32_16x16x32_bf16(vf1, pf, oacc[1][mi], 0, 0, 0);
                dacc[mi]    = __builtin_amdgcn_mfma_f32_16x16x32_bf16(onesf, pf, dacc[mi], 0, 0, 0);
            }
        }
    }

    // ---- epilogue: scale by 1/denominator, write O ----
    ushort_t* Ob = O + base;
#pragma unroll
    for (int mi = 0; mi < 2; ++mi) {
        const float inv = 1.0f / dacc[mi][0];
        const int m = m0 + (w * 2 + mi) * 16 + c;
#pragma unroll
        for (int ssub = 0; ssub < 2; ++ssub)
#pragma unroll
            for (int r = 0; r < 4; ++r)
                Ob[(size_t)(ssub * 16 + quad * 4 + r) * 1024 + m] = f2bf(oacc[ssub][mi][r] * inv);
    }
}

// ---------------------------------------------------------------------------
// Kernel 4: MFMA output projection + bias + residual. Unchanged.
// ---------------------------------------------------------------------------
__global__ __launch_bounds__(256, 4) void oproj_kernel(
    const ushort_t* __restrict__ A, const ushort_t* __restrict__ wo,
    const float* __restrict__ bo, const float* __restrict__ x,
    float* __restrict__ out)
{
    __shared__ __align__(16) ushort_t Al[512 * 8];
    __shared__ __align__(16) ushort_t Wl[512 * 8];

    const int blk = blockIdx.x;
    const int m0  = (blk >> 2) << 6;
    const int n0  = (blk & 3) << 6;
    const int tid = threadIdx.x;
    const int w    = tid >> 6;
    const int lane = tid & 63;
    const int quad = lane >> 4;
    const int c    = lane & 15;

    f32x4 acc[4];
#pragma unroll
    for (int i = 0; i < 4; ++i) acc[i] = (f32x4){0.f, 0.f, 0.f, 0.f};

    for (int kc = 0; kc < 4; ++kc) {
        const int k0 = kc << 6;
        __syncthreads();
#pragma unroll
        for (int i = 0; i < 2; ++i) {
            const int id = tid + i * 256;
            const int kq = id >> 6, mn = id & 63;
            *(bf16x8*)&Al[id * 8] = *(const bf16x8*)&A [(size_t)(m0 + mn) * 256 + k0 + kq * 8];
            *(bf16x8*)&Wl[id * 8] = *(const bf16x8*)&wo[(size_t)(n0 + mn) * 256 + k0 + kq * 8];
        }
        __syncthreads();
#pragma unroll
        for (int ks = 0; ks < 2; ++ks) {
            const int kq = ks * 4 + quad;
            const bf16x8 bw = *(const bf16x8*)&Wl[(kq * 64 + w * 16 + c) * 8];
#pragma unroll
            for (int msub = 0; msub < 4; ++msub) {
                const bf16x8 af = *(const bf16x8*)&Al[(kq * 64 + msub * 16 + c) * 8];
                acc[msub] = __builtin_amdgcn_mfma_f32_16x16x32_bf16(bw, af, acc[msub], 0, 0, 0);
            }
        }
    }

    const int n = n0 + w * 16 + quad * 4;
    const float4 bo4 = *(const float4*)&bo[n];
#pragma unroll
    for (int msub = 0; msub < 4; ++msub) {
        const size_t g = (size_t)(m0 + msub * 16 + c) * 256 + n;
        const float4 r = *(const float4*)&x[g];
        float4 t;
        t.x = acc[msub][0] + bo4.x + r.x;
        t.y = acc[msub][1] + bo4.y + r.y;
        t.z = acc[msub][2] + bo4.z + r.z;
        t.w = acc[msub][3] + bo4.w + r.w;
        *(float4*)&out[g] = t;
    }
}

// ---------------------------------------------------------------------------
extern "C" void kernel_launch(void* const* d_in, const int* in_sizes, int n_in,
                              void* d_out, int out_size, void* d_ws, size_t ws_size,
                              hipStream_t stream)
{
    (void)in_sizes; (void)n_in; (void)out_size; (void)ws_size;
    const float* x   = (const float*)d_in[0];
    const float* lng = (const float*)d_in[1];
    const float* lnb = (const float*)d_in[2];
    const float* wq  = (const float*)d_in[3];
    const float* bq  = (const float*)d_in[4];
    const float* wk  = (const float*)d_in[5];
    const float* bk  = (const float*)d_in[6];
    const float* wv  = (const float*)d_in[7];
    const float* bv  = (const float*)d_in[8];
    const float* wo  = (const float*)d_in[9];
    const float* bo  = (const float*)d_in[10];
    const float* rb  = (const float*)d_in[11];
    // d_in[12] (rel_idx) unused: index recomputed analytically in-kernel.

    ushort_t* ws = (ushort_t*)d_ws;
    ushort_t* Xbf = ws;                       // 4194304 elems each
    ushort_t* Qbf = ws + 1 * 4194304;
    ushort_t* Kbf = ws + 2 * 4194304;
    ushort_t* Vbf = ws + 3 * 4194304;
    ushort_t* Obf = ws + 4 * 4194304;
    ushort_t* Wqb = ws + 5 * 4194304;
    ushort_t* Wkb = Wqb + 65536;
    ushort_t* Wvb = Wkb + 65536;
    ushort_t* Wob = Wvb + 65536;
    float* out = (float*)d_out;

    hipLaunchKernelGGL(wcvt_kernel,  dim3(256),  dim3(256), 0, stream,
                       wq, wk, wv, wo, Wqb, Wkb, Wvb, Wob);
    hipLaunchKernelGGL(ln_kernel,    dim3(256),  dim3(256), 0, stream, x, lng, lnb, Xbf);
    hipLaunchKernelGGL(qkv_kernel,   dim3(1024), dim3(256), 0, stream,
                       Xbf, Wqb, bq, Wkb, bk, Wvb, bv, Qbf, Kbf, Vbf);
    hipLaunchKernelGGL(attn_kernel,  dim3(1024), dim3(256), 0, stream, Qbf, Kbf, Vbf, rb, Obf);
    hipLaunchKernelGGL(oproj_kernel, dim3(1024), dim3(256), 0, stream, Obf, Wob, bo, x, out);
}